// Round 6
// baseline (840.924 us; speedup 1.0000x reference)
//
#include <hip/hip_runtime.h>

// RGCN layer: out[i] = relu( x[i]@root + bias + sum_r mean_{j in N_r(i)} x[j]@W[r] )
//
// Fused tile strategy, MFMA core, latency-optimized gather:
//   prep_misc: WT[seg][n][k] = bf16(Wseg[k][n]) + zero bin cursors
//   hist/scan/bin: edges binned by (dst-tile, rel), packed = src | dl<<26
//   rgcn_fused: 512 threads (8 waves) per 64-node tile.
//     Root segment: A-frags straight from global x (coalesced rows) -> MFMA.
//     Per relation: zero A, gather x[src] with x4-unrolled batched loads
//     (8 outstanding rows/wave) + LDS f32 atomics, 1/cnt scale, frag, MFMA.
//     Wave w = (row-quad w&3, col-half w>>2): 16 rows x 64 cols per wave.

#define D     128
#define TILE  64

typedef __attribute__((ext_vector_type(8))) short  bf16x8;
typedef __attribute__((ext_vector_type(4))) float  f32x4;

__device__ inline unsigned short f32_to_bf16(float f) {
    unsigned u = __float_as_uint(f);
    return (unsigned short)((u + 0x7FFF + ((u >> 16) & 1)) >> 16);   // RNE
}

// ---------------------------------------------------------------------------
// WT[seg][n][k] = bf16( seg==0 ? root[k][n] : W[seg-1][k][n] ); also zero cursor
// ---------------------------------------------------------------------------
__global__ __launch_bounds__(256) void prep_misc(
    const float* __restrict__ W, const float* __restrict__ root,
    unsigned short* __restrict__ WT, int* __restrict__ cursor,
    int nbins, int n_rel)
{
    int idx = blockIdx.x * 256 + threadIdx.x;
    if (idx < nbins) cursor[idx] = 0;
    int total = (n_rel + 1) * D * D;
    if (idx < total) {
        int seg = idx >> 14;              // / (128*128)
        int rem = idx & 16383;
        int n = rem >> 7, k = rem & 127;
        float v = (seg == 0) ? root[k * D + n]
                             : W[(size_t)(seg - 1) * D * D + k * D + n];
        WT[idx] = f32_to_bf16(v);
    }
}

// ---------------------------------------------------------------------------
__global__ __launch_bounds__(256) void edge_hist(
    const int* __restrict__ edge_index, const int* __restrict__ edge_type,
    int* __restrict__ hist, int n_edges, int n_rel)
{
    int e = blockIdx.x * 256 + threadIdx.x;
    if (e >= n_edges) return;
    int dst = edge_index[n_edges + e];
    int r   = edge_type[e];
    atomicAdd(&hist[(dst >> 6) * n_rel + r], 1);
}

// ---------------------------------------------------------------------------
// Exclusive scan of data[n] (in-place, becomes cursor) and into ptr[n+1].
// Single block, 1024 threads.
// ---------------------------------------------------------------------------
__global__ __launch_bounds__(1024) void scan_bins(
    int* __restrict__ data, int* __restrict__ ptr, int n)
{
    __shared__ int buf[2][1024];
    const int tid = threadIdx.x;
    int carry = 0;
    for (int c0 = 0; c0 < n; c0 += 1024) {
        int i = c0 + tid;
        int v = (i < n) ? data[i] : 0;
        buf[0][tid] = v;
        __syncthreads();
        int pi = 0;
        for (int off = 1; off < 1024; off <<= 1) {
            int t = buf[pi][tid] + ((tid >= off) ? buf[pi][tid - off] : 0);
            buf[1 - pi][tid] = t;
            pi = 1 - pi;
            __syncthreads();
        }
        int ex = carry + buf[pi][tid] - v;
        if (i < n) { ptr[i] = ex; data[i] = ex; }
        carry += buf[pi][1023];
        __syncthreads();
    }
    if (tid == 0) ptr[n] = carry;
}

// ---------------------------------------------------------------------------
__global__ __launch_bounds__(256) void edge_bin(
    const int* __restrict__ edge_index, const int* __restrict__ edge_type,
    int* __restrict__ cursor, unsigned* __restrict__ packed, int n_edges, int n_rel)
{
    int e = blockIdx.x * 256 + threadIdx.x;
    if (e >= n_edges) return;
    int src = edge_index[e];
    int dst = edge_index[n_edges + e];
    int r   = edge_type[e];
    int pos = atomicAdd(&cursor[(dst >> 6) * n_rel + r], 1);
    packed[pos] = (unsigned)src | ((unsigned)(dst & 63) << 26);
}

// ---------------------------------------------------------------------------
// Fused aggregate + MFMA GEMM. 512 threads = 8 waves = one 64-node tile.
// Wave w: rows (w&3)*16..+15, cols (w>>2)*64..+63 (4 nt of 16x16x32 MFMA).
// ---------------------------------------------------------------------------
__global__ __launch_bounds__(512, 4) void rgcn_fused(
    const float* __restrict__ x,             // [n_nodes][D]
    const unsigned* __restrict__ packed,     // [n_edges] bin-sorted
    const int* __restrict__ binptr,          // [ntiles*n_rel + 1]
    const unsigned short* __restrict__ WT,   // [n_rel+1][D][D] bf16, n-major
    const float* __restrict__ bias,          // [D]
    float* __restrict__ out,                 // [n_nodes][D]
    int n_nodes, int n_rel)
{
    __shared__ float A[TILE][D + 4];
    __shared__ int   cnt[TILE];

    const int tid   = threadIdx.x;
    const int m0    = blockIdx.x * TILE;
    const int wave  = tid >> 6;              // 0..7
    const int lane  = tid & 63;
    const int l16   = lane & 15;
    const int quad  = lane >> 4;
    const int rbase = (wave & 3) * 16;       // MFMA row base for this wave
    const int chalf = (wave >> 2) * 64;      // MFMA col half for this wave

    f32x4 acc[4];
#pragma unroll
    for (int nt = 0; nt < 4; ++nt) acc[nt] = (f32x4){0.f, 0.f, 0.f, 0.f};

    // ---- root segment: A-frags straight from global x (no LDS round trip) ----
    {
        bf16x8 af[4];
        const int node = m0 + rbase + l16;
        const bool okr = (node < n_nodes);
        const float* xr = x + (size_t)node * D + quad * 8;
#pragma unroll
        for (int kc = 0; kc < 4; ++kc) {
            f32x4 lo = okr ? *(const f32x4*)(xr + kc * 32)
                           : (f32x4){0.f, 0.f, 0.f, 0.f};
            f32x4 hi = okr ? *(const f32x4*)(xr + kc * 32 + 4)
                           : (f32x4){0.f, 0.f, 0.f, 0.f};
            bf16x8 f;
            f[0] = (short)f32_to_bf16(lo[0]);
            f[1] = (short)f32_to_bf16(lo[1]);
            f[2] = (short)f32_to_bf16(lo[2]);
            f[3] = (short)f32_to_bf16(lo[3]);
            f[4] = (short)f32_to_bf16(hi[0]);
            f[5] = (short)f32_to_bf16(hi[1]);
            f[6] = (short)f32_to_bf16(hi[2]);
            f[7] = (short)f32_to_bf16(hi[3]);
            af[kc] = f;
        }
#pragma unroll
        for (int nt = 0; nt < 4; ++nt) {
            const unsigned short* bp = WT + (size_t)(chalf + nt * 16 + l16) * D + quad * 8;
#pragma unroll
            for (int kc = 0; kc < 4; ++kc) {
                bf16x8 bf = *(const bf16x8*)(bp + kc * 32);
                acc[nt] = __builtin_amdgcn_mfma_f32_16x16x32_bf16(af[kc], bf, acc[nt], 0, 0, 0);
            }
        }
    }

    // ---- relation segments ----
    for (int s = 1; s <= n_rel; ++s) {
        const int b  = blockIdx.x * n_rel + (s - 1);
        const int e0 = binptr[b];
        const int e1 = binptr[b + 1];
        if (e0 == e1) continue;              // empty bin (block-uniform)

        __syncthreads();                     // prev segment's frag readers done
        // zero A-tile + counts (512 threads, 4 iters)
#pragma unroll
        for (int i = 0; i < 4; ++i) {
            int idx = tid + i * 512;
            int row = idx >> 5, c4 = idx & 31;
            *(float4*)&A[row][c4 * 4] = make_float4(0.f, 0.f, 0.f, 0.f);
        }
        if (tid < TILE) cnt[tid] = 0;
        __syncthreads();

        // gather + LDS f32 atomics, 4 edges per wave per iteration (8 rows in flight)
        for (int base = e0 + wave * 4; base < e1; base += 32) {
            float va[4], vb[4];
            int   dl[4];
            bool  ok[4];
#pragma unroll
            for (int j = 0; j < 4; ++j) {
                int e = base + j;
                ok[j] = (e < e1);
                unsigned p = ok[j] ? packed[e] : 0u;
                int src = (int)(p & 0x03FFFFFF);
                dl[j] = (int)(p >> 26);
                const float* xs = x + (size_t)src * D;
                va[j] = ok[j] ? xs[lane]      : 0.f;
                vb[j] = ok[j] ? xs[lane + 64] : 0.f;
            }
#pragma unroll
            for (int j = 0; j < 4; ++j) {
                if (ok[j]) {
                    atomicAdd(&A[dl[j]][lane],      va[j]);
                    atomicAdd(&A[dl[j]][lane + 64], vb[j]);
                    if (lane == 0) atomicAdd(&cnt[dl[j]], 1);
                }
            }
        }
        __syncthreads();

        // scale rows by 1/cnt (mean); rows with cnt<=1 need no work
#pragma unroll
        for (int i = 0; i < 4; ++i) {
            int idx = tid + i * 512;
            int row = idx >> 5, c4 = idx & 31;
            int c = cnt[row];
            if (c > 1) {
                float sc = 1.f / (float)c;
                float4 v = *(float4*)&A[row][c4 * 4];
                v.x *= sc; v.y *= sc; v.z *= sc; v.w *= sc;
                *(float4*)&A[row][c4 * 4] = v;
            }
        }
        __syncthreads();

        // A-frags from LDS, B-frags from WT (L2-hot), MFMA
        bf16x8 af[4];
        {
            const int m = rbase + l16;
#pragma unroll
            for (int kc = 0; kc < 4; ++kc) {
                const float* ap = &A[m][kc * 32 + quad * 8];
                f32x4 lo = *(const f32x4*)ap;
                f32x4 hi = *(const f32x4*)(ap + 4);
                bf16x8 f;
                f[0] = (short)f32_to_bf16(lo[0]);
                f[1] = (short)f32_to_bf16(lo[1]);
                f[2] = (short)f32_to_bf16(lo[2]);
                f[3] = (short)f32_to_bf16(lo[3]);
                f[4] = (short)f32_to_bf16(hi[0]);
                f[5] = (short)f32_to_bf16(hi[1]);
                f[6] = (short)f32_to_bf16(hi[2]);
                f[7] = (short)f32_to_bf16(hi[3]);
                af[kc] = f;
            }
        }
        const unsigned short* Wseg = WT + (size_t)s * D * D;
#pragma unroll
        for (int nt = 0; nt < 4; ++nt) {
            const unsigned short* bp = Wseg + (size_t)(chalf + nt * 16 + l16) * D + quad * 8;
#pragma unroll
            for (int kc = 0; kc < 4; ++kc) {
                bf16x8 bf = *(const bf16x8*)(bp + kc * 32);
                acc[nt] = __builtin_amdgcn_mfma_f32_16x16x32_bf16(af[kc], bf, acc[nt], 0, 0, 0);
            }
        }
    }

    // epilogue: bias + relu + store. C/D layout: col=l16, row=quad*4+reg
#pragma unroll
    for (int nt = 0; nt < 4; ++nt) {
        int col = chalf + nt * 16 + l16;
        float bv = bias[col];
#pragma unroll
        for (int reg = 0; reg < 4; ++reg) {
            int node = m0 + rbase + quad * 4 + reg;
            if (node < n_nodes)
                out[(size_t)node * D + col] = fmaxf(acc[nt][reg] + bv, 0.f);
        }
    }
}

extern "C" void kernel_launch(void* const* d_in, const int* in_sizes, int n_in,
                              void* d_out, int out_size, void* d_ws, size_t ws_size,
                              hipStream_t stream) {
    const float* x          = (const float*)d_in[0];
    const int*   edge_index = (const int*)d_in[1];
    const int*   edge_type  = (const int*)d_in[2];
    const float* W          = (const float*)d_in[3];
    const float* root       = (const float*)d_in[4];
    const float* bias       = (const float*)d_in[5];
    float* out = (float*)d_out;

    const int n_nodes = in_sizes[0] / D;          // 100000
    const int n_edges = in_sizes[2];              // 600000
    const int n_rel   = in_sizes[3] / (D * D);    // 8
    const int ntiles  = (n_nodes + TILE - 1) / TILE;
    const int nbins   = ntiles * n_rel;

    // ws layout: binptr[nbins+1] | cursor[nbins] | WT[(n_rel+1)*D*D bf16] | packed[n_edges]
    int* binptr = (int*)d_ws;
    int* cursor = binptr + ((nbins + 1 + 63) & ~63);
    unsigned short* WT = (unsigned short*)(cursor + ((nbins + 63) & ~63));
    size_t wt_elems = (size_t)(n_rel + 1) * D * D;
    unsigned* packed = (unsigned*)(WT + ((wt_elems + 127) & ~(size_t)127));

    const int egrid = (n_edges + 255) / 256;
    int prep_n = (int)wt_elems; if (nbins > prep_n) prep_n = nbins;
    const int pgrid = (prep_n + 255) / 256;

    prep_misc<<<pgrid, 256, 0, stream>>>(W, root, WT, cursor, nbins, n_rel);
    edge_hist<<<egrid, 256, 0, stream>>>(edge_index, edge_type, cursor, n_edges, n_rel);
    scan_bins<<<1, 1024, 0, stream>>>(cursor, binptr, nbins);
    edge_bin<<<egrid, 256, 0, stream>>>(edge_index, edge_type, cursor, packed, n_edges, n_rel);
    rgcn_fused<<<ntiles, 512, 0, stream>>>(
        x, packed, binptr, WT, bias, out, n_nodes, n_rel);
}

// Round 7
// 807.316 us; speedup vs baseline: 1.0416x; 1.0416x over previous
//
#include <hip/hip_runtime.h>

// RGCN layer: out[i] = relu( x[i]@root + bias + sum_r mean_{j in N_r(i)} x[j]@W[r] )
//
// Fused tile strategy, MFMA core, software-pipelined segments:
//   prep_xb:   XB = bf16(x)  (gather payload halved; one dword/lane per row)
//   prep_misc: WT[seg][n][k] = bf16(Wseg[k][n]) + zero bin cursors
//   hist/scan/bin: edges binned by (dst-tile, rel), packed = src | dl<<26
//   rgcn_fused: 512 threads (8 waves) per 64-node tile. Per-block edge list
//     staged in LDS once. Pipeline: prefetch segment s+1's edge rows into
//     REGISTERS while segment s is scaled/fragged/MFMA'd; LDS f32 atomics
//     apply the already-resident rows at iteration start. 3 barriers/segment.

#define D     128
#define TILE  64
#define PKCAP 2048   // LDS-staged packed entries per tile (8 KB)

typedef __attribute__((ext_vector_type(8))) short  bf16x8;
typedef __attribute__((ext_vector_type(4))) float  f32x4;

__device__ inline unsigned short f32_to_bf16(float f) {
    unsigned u = __float_as_uint(f);
    return (unsigned short)((u + 0x7FFF + ((u >> 16) & 1)) >> 16);   // RNE
}

// ---------------------------------------------------------------------------
__global__ __launch_bounds__(256) void prep_xb(
    const float* __restrict__ x, unsigned* __restrict__ XB, int nquads)
{
    int i = blockIdx.x * 256 + threadIdx.x;
    if (i >= nquads) return;
    float4 v = ((const float4*)x)[i];
    unsigned w0 = (unsigned)f32_to_bf16(v.x) | ((unsigned)f32_to_bf16(v.y) << 16);
    unsigned w1 = (unsigned)f32_to_bf16(v.z) | ((unsigned)f32_to_bf16(v.w) << 16);
    ((uint2*)XB)[i] = make_uint2(w0, w1);
}

// ---------------------------------------------------------------------------
// WT[seg][n][k] = bf16( seg==0 ? root[k][n] : W[seg-1][k][n] ); also zero cursor
// ---------------------------------------------------------------------------
__global__ __launch_bounds__(256) void prep_misc(
    const float* __restrict__ W, const float* __restrict__ root,
    unsigned short* __restrict__ WT, int* __restrict__ cursor,
    int nbins, int n_rel)
{
    int idx = blockIdx.x * 256 + threadIdx.x;
    if (idx < nbins) cursor[idx] = 0;
    int total = (n_rel + 1) * D * D;
    if (idx < total) {
        int seg = idx >> 14;
        int rem = idx & 16383;
        int n = rem >> 7, k = rem & 127;
        float v = (seg == 0) ? root[k * D + n]
                             : W[(size_t)(seg - 1) * D * D + k * D + n];
        WT[idx] = f32_to_bf16(v);
    }
}

// ---------------------------------------------------------------------------
__global__ __launch_bounds__(256) void edge_hist(
    const int* __restrict__ edge_index, const int* __restrict__ edge_type,
    int* __restrict__ hist, int n_edges, int n_rel)
{
    int e = blockIdx.x * 256 + threadIdx.x;
    if (e >= n_edges) return;
    int dst = edge_index[n_edges + e];
    int r   = edge_type[e];
    atomicAdd(&hist[(dst >> 6) * n_rel + r], 1);
}

// ---------------------------------------------------------------------------
__global__ __launch_bounds__(1024) void scan_bins(
    int* __restrict__ data, int* __restrict__ ptr, int n)
{
    __shared__ int buf[2][1024];
    const int tid = threadIdx.x;
    int carry = 0;
    for (int c0 = 0; c0 < n; c0 += 1024) {
        int i = c0 + tid;
        int v = (i < n) ? data[i] : 0;
        buf[0][tid] = v;
        __syncthreads();
        int pi = 0;
        for (int off = 1; off < 1024; off <<= 1) {
            int t = buf[pi][tid] + ((tid >= off) ? buf[pi][tid - off] : 0);
            buf[1 - pi][tid] = t;
            pi = 1 - pi;
            __syncthreads();
        }
        int ex = carry + buf[pi][tid] - v;
        if (i < n) { ptr[i] = ex; data[i] = ex; }
        carry += buf[pi][1023];
        __syncthreads();
    }
    if (tid == 0) ptr[n] = carry;
}

// ---------------------------------------------------------------------------
__global__ __launch_bounds__(256) void edge_bin(
    const int* __restrict__ edge_index, const int* __restrict__ edge_type,
    int* __restrict__ cursor, unsigned* __restrict__ packed, int n_edges, int n_rel)
{
    int e = blockIdx.x * 256 + threadIdx.x;
    if (e >= n_edges) return;
    int src = edge_index[e];
    int dst = edge_index[n_edges + e];
    int r   = edge_type[e];
    int pos = atomicAdd(&cursor[(dst >> 6) * n_rel + r], 1);
    packed[pos] = (unsigned)src | ((unsigned)(dst & 63) << 26);
}

// ---------------------------------------------------------------------------
// Fused aggregate + MFMA GEMM, software-pipelined.
// 512 threads = 8 waves = one 64-node tile.
// Wave w: rows (w&3)*16..+15, cols (w>>2)*64..+63 (4 nt of 16x16x32 MFMA).
// ---------------------------------------------------------------------------
__global__ __launch_bounds__(512, 4) void rgcn_fused(
    const unsigned* __restrict__ XB,         // [n_nodes][64] words (2 bf16 each)
    const unsigned* __restrict__ packed,     // [n_edges] bin-sorted
    const int* __restrict__ binptr,          // [ntiles*n_rel + 1]
    const unsigned short* __restrict__ WT,   // [n_rel+1][D][D] bf16, n-major
    const float* __restrict__ bias,          // [D]
    float* __restrict__ out,                 // [n_nodes][D]
    int n_nodes, int n_rel)
{
    __shared__ float    A[TILE][D + 4];
    __shared__ int      cnt[TILE];
    __shared__ unsigned pk[PKCAP];

    const int tid   = threadIdx.x;
    const int m0    = blockIdx.x * TILE;
    const int wave  = tid >> 6;              // 0..7
    const int lane  = tid & 63;
    const int l16   = lane & 15;
    const int quad  = lane >> 4;
    const int rbase = (wave & 3) * 16;
    const int chalf = (wave >> 2) * 64;
    const int bb    = blockIdx.x * n_rel;

    f32x4 acc[4];
#pragma unroll
    for (int nt = 0; nt < 4; ++nt) acc[nt] = (f32x4){0.f, 0.f, 0.f, 0.f};

    // ---- stage this tile's whole packed edge range into LDS ----
    const int tb0 = binptr[bb];
    const int tb1 = binptr[bb + n_rel];
    {
        int len = tb1 - tb0; if (len > PKCAP) len = PKCAP;
        for (int i = tid; i < len; i += 512) pk[i] = packed[tb0 + i];
    }
    // zero A + cnt
#pragma unroll
    for (int i = 0; i < 4; ++i) {
        int idx = tid + i * 512;
        *(float4*)&A[idx >> 5][(idx & 31) * 4] = make_float4(0.f, 0.f, 0.f, 0.f);
    }
    if (tid < TILE) cnt[tid] = 0;
    __syncthreads();        // pk staged, A zeroed

    // ---- prefetch segment 1's edge rows into registers ----
    unsigned pval[8];
    int      pdl[8];
    int e0 = tb0, e1 = binptr[bb + 1];
    auto prefetch = [&](int pe0, int pe1) {
#pragma unroll
        for (int i = 0; i < 8; ++i) {
            int e = pe0 + wave + i * 8;
            bool ok = (e < pe1);
            unsigned p = 0u;
            if (ok) {
                int idx = e - tb0;
                p = (idx < PKCAP) ? pk[idx] : packed[e];
            }
            pdl[i]  = ok ? (int)(p >> 26) : -1;
            pval[i] = ok ? XB[(size_t)(p & 0x03FFFFFF) * 64 + lane] : 0u;
        }
    };
    prefetch(e0, e1);

    // ---- root segment: A-frags straight from XB (bf16, no conversion) ----
    {
        const int node = m0 + rbase + l16;
        const bool okr = (node < n_nodes);
        const unsigned short* xr = (const unsigned short*)XB
                                   + (size_t)node * D + quad * 8;
        bf16x8 af[4];
#pragma unroll
        for (int kc = 0; kc < 4; ++kc)
            af[kc] = okr ? *(const bf16x8*)(xr + kc * 32)
                         : (bf16x8){0, 0, 0, 0, 0, 0, 0, 0};
#pragma unroll
        for (int nt = 0; nt < 4; ++nt) {
            const unsigned short* bp = WT + (size_t)(chalf + nt * 16 + l16) * D + quad * 8;
#pragma unroll
            for (int kc = 0; kc < 4; ++kc) {
                bf16x8 bf = *(const bf16x8*)(bp + kc * 32);
                acc[nt] = __builtin_amdgcn_mfma_f32_16x16x32_bf16(af[kc], bf, acc[nt], 0, 0, 0);
            }
        }
    }

    // ---- pipelined relation segments ----
    for (int s = 1; s <= n_rel; ++s) {
        // apply prefetched rows (LDS f32 atomics); loads were issued an
        // iteration ago, so vmcnt is (nearly) satisfied.
#pragma unroll
        for (int i = 0; i < 8; ++i) {
            if (pdl[i] >= 0) {
                unsigned u = pval[i];
                float lo = __uint_as_float(u << 16);
                float hi = __uint_as_float(u & 0xFFFF0000u);
                atomicAdd(&A[pdl[i]][2 * lane],     lo);
                atomicAdd(&A[pdl[i]][2 * lane + 1], hi);
                if (lane == 0) atomicAdd(&cnt[pdl[i]], 1);
            }
        }
        // tail (bins with >64 edges — rare)
        for (int e = e0 + 64 + wave; e < e1; e += 8) {
            int idx = e - tb0;
            unsigned p = (idx < PKCAP) ? pk[idx] : packed[e];
            unsigned u = XB[(size_t)(p & 0x03FFFFFF) * 64 + lane];
            int dl = (int)(p >> 26);
            atomicAdd(&A[dl][2 * lane],     __uint_as_float(u << 16));
            atomicAdd(&A[dl][2 * lane + 1], __uint_as_float(u & 0xFFFF0000u));
            if (lane == 0) atomicAdd(&cnt[dl], 1);
        }
        const bool nonempty = (e1 > e0);
        int ne0 = 0, ne1 = 0;
        if (s < n_rel) { ne0 = e1; ne1 = binptr[bb + s + 1]; }
        __syncthreads();                 // segment s aggregation complete

        // frag A with mean-scale folded in
        bf16x8 af[4];
        if (nonempty) {
            const int m = rbase + l16;
            int c = cnt[m];
            float sc = (c > 1) ? 1.f / (float)c : 1.f;
#pragma unroll
            for (int kc = 0; kc < 4; ++kc) {
                const float* ap = &A[m][kc * 32 + quad * 8];
                f32x4 lo = *(const f32x4*)ap;
                f32x4 hi = *(const f32x4*)(ap + 4);
                bf16x8 f;
                f[0] = (short)f32_to_bf16(lo[0] * sc);
                f[1] = (short)f32_to_bf16(lo[1] * sc);
                f[2] = (short)f32_to_bf16(lo[2] * sc);
                f[3] = (short)f32_to_bf16(lo[3] * sc);
                f[4] = (short)f32_to_bf16(hi[0] * sc);
                f[5] = (short)f32_to_bf16(hi[1] * sc);
                f[6] = (short)f32_to_bf16(hi[2] * sc);
                f[7] = (short)f32_to_bf16(hi[3] * sc);
                af[kc] = f;
            }
        }
        __syncthreads();                 // all frag reads of A done

        if (s < n_rel) {
            // zero A + cnt for s+1, then issue s+1's gather loads (registers)
#pragma unroll
            for (int i = 0; i < 4; ++i) {
                int idx = tid + i * 512;
                *(float4*)&A[idx >> 5][(idx & 31) * 4] = make_float4(0.f, 0.f, 0.f, 0.f);
            }
            if (tid < TILE) cnt[tid] = 0;
            prefetch(ne0, ne1);
        }

        // MFMA for segment s (independent of A) — covers prefetch latency
        if (nonempty) {
            const unsigned short* Wseg = WT + (size_t)s * D * D;
#pragma unroll
            for (int nt = 0; nt < 4; ++nt) {
                const unsigned short* bp = Wseg + (size_t)(chalf + nt * 16 + l16) * D + quad * 8;
#pragma unroll
                for (int kc = 0; kc < 4; ++kc) {
                    bf16x8 bf = *(const bf16x8*)(bp + kc * 32);
                    acc[nt] = __builtin_amdgcn_mfma_f32_16x16x32_bf16(af[kc], bf, acc[nt], 0, 0, 0);
                }
            }
        }
        e0 = ne0; e1 = ne1;
        if (s < n_rel) __syncthreads();  // zero complete before next apply
    }

    // epilogue: bias + relu + store. C/D layout: col=l16, row=quad*4+reg
#pragma unroll
    for (int nt = 0; nt < 4; ++nt) {
        int col = chalf + nt * 16 + l16;
        float bv = bias[col];
#pragma unroll
        for (int reg = 0; reg < 4; ++reg) {
            int node = m0 + rbase + quad * 4 + reg;
            if (node < n_nodes)
                out[(size_t)node * D + col] = fmaxf(acc[nt][reg] + bv, 0.f);
        }
    }
}

extern "C" void kernel_launch(void* const* d_in, const int* in_sizes, int n_in,
                              void* d_out, int out_size, void* d_ws, size_t ws_size,
                              hipStream_t stream) {
    const float* x          = (const float*)d_in[0];
    const int*   edge_index = (const int*)d_in[1];
    const int*   edge_type  = (const int*)d_in[2];
    const float* W          = (const float*)d_in[3];
    const float* root       = (const float*)d_in[4];
    const float* bias       = (const float*)d_in[5];
    float* out = (float*)d_out;

    const int n_nodes = in_sizes[0] / D;          // 100000
    const int n_edges = in_sizes[2];              // 600000
    const int n_rel   = in_sizes[3] / (D * D);    // 8
    const int ntiles  = (n_nodes + TILE - 1) / TILE;
    const int nbins   = ntiles * n_rel;

    // ws layout: binptr | cursor | WT | XB | packed
    int* binptr = (int*)d_ws;
    int* cursor = binptr + ((nbins + 1 + 63) & ~63);
    unsigned short* WT = (unsigned short*)(cursor + ((nbins + 63) & ~63));
    size_t wt_elems = (size_t)(n_rel + 1) * D * D;
    unsigned* XB = (unsigned*)(WT + ((wt_elems + 127) & ~(size_t)127));
    size_t xb_words = (size_t)n_nodes * (D / 2);
    unsigned* packed = XB + ((xb_words + 127) & ~(size_t)127);

    const int egrid = (n_edges + 255) / 256;
    int prep_n = (int)wt_elems; if (nbins > prep_n) prep_n = nbins;
    const int pgrid = (prep_n + 255) / 256;
    const int nquads = n_nodes * (D / 4);
    const int xgrid = (nquads + 255) / 256;

    prep_xb<<<xgrid, 256, 0, stream>>>(x, XB, nquads);
    prep_misc<<<pgrid, 256, 0, stream>>>(W, root, WT, cursor, nbins, n_rel);
    edge_hist<<<egrid, 256, 0, stream>>>(edge_index, edge_type, cursor, n_edges, n_rel);
    scan_bins<<<1, 1024, 0, stream>>>(cursor, binptr, nbins);
    edge_bin<<<egrid, 256, 0, stream>>>(edge_index, edge_type, cursor, packed, n_edges, n_rel);
    rgcn_fused<<<ntiles, 512, 0, stream>>>(
        XB, packed, binptr, WT, bias, out, n_nodes, n_rel);
}

// Round 8
// 543.391 us; speedup vs baseline: 1.5475x; 1.4857x over previous
//
#include <hip/hip_runtime.h>

// RGCN layer: out[i] = relu( x[i]@root + bias + sum_r mean_{j in N_r(i)} x[j]@W[r] )
//
// Two-phase, barrier-free restructure (linearity):
//   H[0] = bf16(x@root + bias); H[s] = bf16(x@W[s-1])        (dense MFMA GEMMs)
//   out[i] = relu( H[0][i] + sum_{e: dst=i} (1/c[i,r_e]) * H[r_e+1][src_e] )
// Phase 2 is one independent wave per dst node: no LDS, no barriers, no atomics.
// H chunked over segments to fit ws (pass structure fixed by ws_size).

#define D 128

typedef __attribute__((ext_vector_type(8))) short bf16x8;
typedef __attribute__((ext_vector_type(4))) float f32x4;

__device__ inline unsigned short f32_to_bf16(float f) {
    unsigned u = __float_as_uint(f);
    return (unsigned short)((u + 0x7FFF + ((u >> 16) & 1)) >> 16);   // RNE
}
__device__ inline float bf_lo(unsigned u) { return __uint_as_float(u << 16); }
__device__ inline float bf_hi(unsigned u) { return __uint_as_float(u & 0xFFFF0000u); }

// ---------------------------------------------------------------------------
// prep: XB = bf16(x); WT[seg][n][k] = bf16(Wseg[k][n]); zero c[] and hd[]
// ---------------------------------------------------------------------------
__global__ __launch_bounds__(256) void prep_all(
    const float* __restrict__ x, const float* __restrict__ W,
    const float* __restrict__ root,
    unsigned* __restrict__ XB, unsigned short* __restrict__ WT,
    int* __restrict__ c, int* __restrict__ hd,
    int nquads, int wt_total, int n_nodes, int n_rel)
{
    int i = blockIdx.x * 256 + threadIdx.x;
    if (i < nquads) {
        float4 v = ((const float4*)x)[i];
        unsigned w0 = (unsigned)f32_to_bf16(v.x) | ((unsigned)f32_to_bf16(v.y) << 16);
        unsigned w1 = (unsigned)f32_to_bf16(v.z) | ((unsigned)f32_to_bf16(v.w) << 16);
        ((uint2*)XB)[i] = make_uint2(w0, w1);
    }
    if (i < wt_total) {
        int seg = i >> 14, rem = i & 16383;
        int n = rem >> 7, k = rem & 127;
        float v = (seg == 0) ? root[k * D + n]
                             : W[(size_t)(seg - 1) * D * D + k * D + n];
        WT[i] = f32_to_bf16(v);
    }
    if (i < n_nodes * n_rel) c[i] = 0;
    if (i < n_nodes) hd[i] = 0;
}

// ---------------------------------------------------------------------------
__global__ __launch_bounds__(256) void edge_hist(
    const int* __restrict__ edge_index, const int* __restrict__ edge_type,
    int* __restrict__ c, int* __restrict__ hd, int n_edges, int n_rel)
{
    int e = blockIdx.x * 256 + threadIdx.x;
    if (e >= n_edges) return;
    int dst = edge_index[n_edges + e];
    int r   = edge_type[e];
    atomicAdd(&c[dst * n_rel + r], 1);
    atomicAdd(&hd[dst], 1);
}

// ---------------------------------------------------------------------------
// Two-level exclusive scan of hd[n] -> rowptr/cursor
// ---------------------------------------------------------------------------
__global__ __launch_bounds__(1024) void scanA(
    const int* __restrict__ hd, int* __restrict__ tmp, int* __restrict__ parts, int n)
{
    __shared__ int buf[2][1024];
    const int tid = threadIdx.x;
    int i = blockIdx.x * 1024 + tid;
    int v = (i < n) ? hd[i] : 0;
    buf[0][tid] = v;
    __syncthreads();
    int pi = 0;
    for (int off = 1; off < 1024; off <<= 1) {
        int t = buf[pi][tid] + ((tid >= off) ? buf[pi][tid - off] : 0);
        buf[1 - pi][tid] = t;
        pi = 1 - pi;
        __syncthreads();
    }
    if (i < n) tmp[i] = buf[pi][tid] - v;           // block-local exclusive
    if (tid == 1023) parts[blockIdx.x] = buf[pi][1023];
}

__global__ __launch_bounds__(128) void scanB(
    const int* __restrict__ parts, int* __restrict__ offs,
    int* __restrict__ rowptr, int np, int n)
{
    __shared__ int buf[2][128];
    const int t = threadIdx.x;
    int v = (t < np) ? parts[t] : 0;
    buf[0][t] = v;
    __syncthreads();
    int pi = 0;
    for (int off = 1; off < 128; off <<= 1) {
        int s = buf[pi][t] + ((t >= off) ? buf[pi][t - off] : 0);
        buf[1 - pi][t] = s;
        pi = 1 - pi;
        __syncthreads();
    }
    if (t < np) offs[t] = buf[pi][t] - v;
    if (t == 0) rowptr[n] = buf[pi][127];           // total = n_edges
}

__global__ __launch_bounds__(1024) void scanC(
    const int* __restrict__ tmp, const int* __restrict__ offs,
    int* __restrict__ rowptr, int* __restrict__ cursor, int n)
{
    int i = blockIdx.x * 1024 + threadIdx.x;
    if (i < n) {
        int v = tmp[i] + offs[blockIdx.x];
        rowptr[i] = v;
        cursor[i] = v;
    }
}

// ---------------------------------------------------------------------------
__global__ __launch_bounds__(256) void edge_bin(
    const int* __restrict__ edge_index, const int* __restrict__ edge_type,
    int* __restrict__ cursor, unsigned* __restrict__ pk2, int n_edges)
{
    int e = blockIdx.x * 256 + threadIdx.x;
    if (e >= n_edges) return;
    int src = edge_index[e];
    int dst = edge_index[n_edges + e];
    int r   = edge_type[e];
    int pos = atomicAdd(&cursor[dst], 1);
    pk2[pos] = (unsigned)src | ((unsigned)r << 17);   // src<2^17, rel 3 bits
}

// ---------------------------------------------------------------------------
// Phase 1: H[sgl][node][128] = bf16( X @ WTseg (+bias if seg 0) )
// Block = 256 thr = 4 waves = 64 rows x 128 cols. Wave w: rows w*16..+15.
// ---------------------------------------------------------------------------
__global__ __launch_bounds__(256) void gemm_h(
    const unsigned* __restrict__ XB, const unsigned short* __restrict__ WT,
    const float* __restrict__ bias, unsigned short* __restrict__ H,
    int n_nodes, int segbase)
{
    __shared__ unsigned short Ht[64][D];   // 16 KB repack tile

    const int sgl = blockIdx.y;            // chunk-local seg
    const int sgg = segbase + sgl;         // global seg (WT/bias)
    const int tid  = threadIdx.x;
    const int m0   = blockIdx.x * 64;
    const int wave = tid >> 6;
    const int lane = tid & 63;
    const int l16  = lane & 15;
    const int quad = lane >> 4;

    // A-frags straight from XB (coalesced rows)
    const int node = m0 + wave * 16 + l16;
    const bool okr = (node < n_nodes);
    const unsigned short* xr = (const unsigned short*)XB + (size_t)node * D + quad * 8;
    bf16x8 af[4];
#pragma unroll
    for (int kc = 0; kc < 4; ++kc)
        af[kc] = okr ? *(const bf16x8*)(xr + kc * 32)
                     : (bf16x8){0, 0, 0, 0, 0, 0, 0, 0};

    const unsigned short* Wseg = WT + (size_t)sgg * D * D;
    f32x4 acc[8];
#pragma unroll
    for (int nt = 0; nt < 8; ++nt) {
        acc[nt] = (f32x4){0.f, 0.f, 0.f, 0.f};
        const unsigned short* bp = Wseg + (size_t)(nt * 16 + l16) * D + quad * 8;
#pragma unroll
        for (int kc = 0; kc < 4; ++kc) {
            bf16x8 bf = *(const bf16x8*)(bp + kc * 32);
            acc[nt] = __builtin_amdgcn_mfma_f32_16x16x32_bf16(af[kc], bf, acc[nt], 0, 0, 0);
        }
    }

    // repack C/D layout -> row-major bf16 tile in LDS
#pragma unroll
    for (int nt = 0; nt < 8; ++nt) {
        int col = nt * 16 + l16;
        float bv = (sgg == 0) ? bias[col] : 0.f;
#pragma unroll
        for (int reg = 0; reg < 4; ++reg)
            Ht[wave * 16 + quad * 4 + reg][col] = f32_to_bf16(acc[nt][reg] + bv);
    }
    __syncthreads();

    // coalesced store (uint4 = 8 bf16)
    int rows = n_nodes - m0; if (rows > 64) rows = 64;
    int nu4 = rows * D / 8;
    const uint4* srcp = (const uint4*)&Ht[0][0];
    uint4* dstp = (uint4*)(H + ((size_t)sgl * n_nodes + m0) * D);
    for (int i = tid; i < nu4; i += 256) dstp[i] = srcp[i];
}

// ---------------------------------------------------------------------------
// Phase 2: one wave per dst node. No LDS, no barriers, no atomics.
// lane owns cols {2*lane, 2*lane+1}.
// ---------------------------------------------------------------------------
__global__ __launch_bounds__(256) void gather_out(
    const unsigned short* __restrict__ H, const unsigned* __restrict__ pk2,
    const int* __restrict__ rowptr, const int* __restrict__ c,
    float* __restrict__ out, int n_nodes, int n_rel,
    int segbase, int segend, int first, int last)
{
    const int dst  = (blockIdx.x * 256 + threadIdx.x) >> 6;
    const int lane = threadIdx.x & 63;
    if (dst >= n_nodes) return;

    const unsigned* HH = (const unsigned*)H;
    float a0, a1;
    if (first) {                                   // seg 0 (root+bias) is chunk-local 0
        unsigned u = HH[(size_t)dst * 64 + lane];
        a0 = bf_lo(u); a1 = bf_hi(u);
    } else {
        float2 o = *(const float2*)(out + (size_t)dst * D + 2 * lane);
        a0 = o.x; a1 = o.y;
    }

    const int e0 = rowptr[dst], e1 = rowptr[dst + 1];
    const int s0 = first ? 1 : segbase;            // relation segs in this pass
    for (int base = e0; base < e1; base += 4) {
        unsigned hv[4]; float al[4]; bool ok[4];
#pragma unroll
        for (int j = 0; j < 4; ++j) {
            int e = base + j;
            bool valid = (e < e1);
            unsigned p = valid ? pk2[e] : 0u;
            int r = (int)(p >> 17);
            int seg = r + 1;
            ok[j] = valid && (seg >= s0) && (seg < segend);
            int src = (int)(p & 0x1FFFF);
            al[j] = ok[j] ? 1.0f / (float)c[dst * n_rel + r] : 0.f;
            hv[j] = ok[j] ? HH[((size_t)(seg - segbase) * n_nodes + src) * 64 + lane] : 0u;
        }
#pragma unroll
        for (int j = 0; j < 4; ++j) {
            if (ok[j]) {
                a0 += al[j] * bf_lo(hv[j]);
                a1 += al[j] * bf_hi(hv[j]);
            }
        }
    }

    if (last) { a0 = fmaxf(a0, 0.f); a1 = fmaxf(a1, 0.f); }
    *(float2*)(out + (size_t)dst * D + 2 * lane) = make_float2(a0, a1);
}

extern "C" void kernel_launch(void* const* d_in, const int* in_sizes, int n_in,
                              void* d_out, int out_size, void* d_ws, size_t ws_size,
                              hipStream_t stream) {
    const float* x          = (const float*)d_in[0];
    const int*   edge_index = (const int*)d_in[1];
    const int*   edge_type  = (const int*)d_in[2];
    const float* W          = (const float*)d_in[3];
    const float* root       = (const float*)d_in[4];
    const float* bias       = (const float*)d_in[5];
    float* out = (float*)d_out;

    const int n_nodes = in_sizes[0] / D;          // 100000
    const int n_edges = in_sizes[2];              // 600000
    const int n_rel   = in_sizes[3] / (D * D);    // 8
    const int nsegs   = n_rel + 1;

    // ws layout
    char* p = (char*)d_ws;
    auto alloc = [&](size_t bytes) {
        char* q = p; p += (bytes + 255) & ~(size_t)255; return q;
    };
    int* c      = (int*)alloc((size_t)n_nodes * n_rel * 4);
    int* hd     = (int*)alloc((size_t)n_nodes * 4);
    int* tmp    = (int*)alloc((size_t)n_nodes * 4);
    int* parts  = (int*)alloc(512);
    int* offs   = (int*)alloc(512);
    int* rowptr = (int*)alloc((size_t)(n_nodes + 1) * 4);
    int* cursor = (int*)alloc((size_t)n_nodes * 4);
    unsigned* pk2 = (unsigned*)alloc((size_t)n_edges * 4);
    unsigned* XB  = (unsigned*)alloc((size_t)n_nodes * (D / 2) * 4);
    unsigned short* WT = (unsigned short*)alloc((size_t)nsegs * D * D * 2);
    size_t used = (size_t)(p - (char*)d_ws);
    size_t per_seg = (((size_t)n_nodes * D * 2) + 255) & ~(size_t)255;
    size_t avail = (ws_size > used) ? ws_size - used : 0;
    int segchunk = (int)(avail / per_seg);
    if (segchunk > nsegs) segchunk = nsegs;
    if (segchunk < 1) segchunk = 1;
    unsigned short* H = (unsigned short*)p;

    const int nquads   = n_nodes * (D / 4);
    const int wt_total = nsegs * D * D;
    int prep_n = nquads;
    if (wt_total > prep_n) prep_n = wt_total;
    if (n_nodes * n_rel > prep_n) prep_n = n_nodes * n_rel;

    const int egrid = (n_edges + 255) / 256;
    const int nA = (n_nodes + 1023) / 1024;       // 98 <= 128

    prep_all<<<(prep_n + 255) / 256, 256, 0, stream>>>(
        x, W, root, XB, WT, c, hd, nquads, wt_total, n_nodes, n_rel);
    edge_hist<<<egrid, 256, 0, stream>>>(edge_index, edge_type, c, hd, n_edges, n_rel);
    scanA<<<nA, 1024, 0, stream>>>(hd, tmp, parts, n_nodes);
    scanB<<<1, 128, 0, stream>>>(parts, offs, rowptr, nA, n_nodes);
    scanC<<<nA, 1024, 0, stream>>>(tmp, offs, rowptr, cursor, n_nodes);
    edge_bin<<<egrid, 256, 0, stream>>>(edge_index, edge_type, cursor, pk2, n_edges);

    const int gtiles = (n_nodes + 63) / 64;
    const int ggrid  = (n_nodes + 3) / 4;         // 4 dst-waves per block
    for (int sb = 0; sb < nsegs; sb += segchunk) {
        int sc = nsegs - sb; if (sc > segchunk) sc = segchunk;
        gemm_h<<<dim3(gtiles, sc), 256, 0, stream>>>(XB, WT, bias, H, n_nodes, sb);
        gather_out<<<ggrid, 256, 0, stream>>>(
            H, pk2, rowptr, c, out, n_nodes, n_rel,
            sb, sb + sc, (sb == 0) ? 1 : 0, (sb + sc == nsegs) ? 1 : 0);
    }
}

// Round 9
// 373.669 us; speedup vs baseline: 2.2505x; 1.4542x over previous
//
#include <hip/hip_runtime.h>

// RGCN layer: out[i] = relu( x[i]@root + bias + sum_r mean_{j in N_r(i)} x[j]@W[r] )
//
// Two-phase, barrier-free restructure (linearity):
//   H[0] = bf16(x@root + bias); H[s] = bf16(x@W[s-1])        (dense MFMA GEMMs)
//   out[i] = relu( H[0][i] + sum_{e: dst=i} (1/c[i,r_e]) * H[r_e+1][src_e] )
// gemm_h v2: 56x9 fat blocks, 28 node-tiles each; B-frags register-resident
// (loaded once per block); raw lgkm-only barrier (stores/prefetch stay in
// flight); double-buffered repack tile. Phase 2: one wave per dst node.

#define D 128

typedef __attribute__((ext_vector_type(8))) short bf16x8;
typedef __attribute__((ext_vector_type(4))) float f32x4;

__device__ inline unsigned short f32_to_bf16(float f) {
    unsigned u = __float_as_uint(f);
    return (unsigned short)((u + 0x7FFF + ((u >> 16) & 1)) >> 16);   // RNE
}
__device__ inline float bf_lo(unsigned u) { return __uint_as_float(u << 16); }
__device__ inline float bf_hi(unsigned u) { return __uint_as_float(u & 0xFFFF0000u); }

// LDS-only barrier: order ds ops without draining vmcnt (global stores /
// prefetch loads remain in flight across it).
__device__ inline void lds_barrier() {
    asm volatile("s_waitcnt lgkmcnt(0)\n\ts_barrier" ::: "memory");
}

// ---------------------------------------------------------------------------
// prep: XB = bf16(x); WT[seg][n][k] = bf16(Wseg[k][n]); zero c[] and hd[]
// ---------------------------------------------------------------------------
__global__ __launch_bounds__(256) void prep_all(
    const float* __restrict__ x, const float* __restrict__ W,
    const float* __restrict__ root,
    unsigned* __restrict__ XB, unsigned short* __restrict__ WT,
    int* __restrict__ c, int* __restrict__ hd,
    int nquads, int wt_total, int n_nodes, int n_rel)
{
    int i = blockIdx.x * 256 + threadIdx.x;
    if (i < nquads) {
        float4 v = ((const float4*)x)[i];
        unsigned w0 = (unsigned)f32_to_bf16(v.x) | ((unsigned)f32_to_bf16(v.y) << 16);
        unsigned w1 = (unsigned)f32_to_bf16(v.z) | ((unsigned)f32_to_bf16(v.w) << 16);
        ((uint2*)XB)[i] = make_uint2(w0, w1);
    }
    if (i < wt_total) {
        int seg = i >> 14, rem = i & 16383;
        int n = rem >> 7, k = rem & 127;
        float v = (seg == 0) ? root[k * D + n]
                             : W[(size_t)(seg - 1) * D * D + k * D + n];
        WT[i] = f32_to_bf16(v);
    }
    if (i < n_nodes * n_rel) c[i] = 0;
    if (i < n_nodes) hd[i] = 0;
}

// ---------------------------------------------------------------------------
__global__ __launch_bounds__(256) void edge_hist(
    const int* __restrict__ edge_index, const int* __restrict__ edge_type,
    int* __restrict__ c, int* __restrict__ hd, int n_edges, int n_rel)
{
    int e = blockIdx.x * 256 + threadIdx.x;
    if (e >= n_edges) return;
    int dst = edge_index[n_edges + e];
    int r   = edge_type[e];
    atomicAdd(&c[dst * n_rel + r], 1);
    atomicAdd(&hd[dst], 1);
}

// ---------------------------------------------------------------------------
// Two-level exclusive scan of hd[n] -> rowptr/cursor
// ---------------------------------------------------------------------------
__global__ __launch_bounds__(1024) void scanA(
    const int* __restrict__ hd, int* __restrict__ tmp, int* __restrict__ parts, int n)
{
    __shared__ int buf[2][1024];
    const int tid = threadIdx.x;
    int i = blockIdx.x * 1024 + tid;
    int v = (i < n) ? hd[i] : 0;
    buf[0][tid] = v;
    __syncthreads();
    int pi = 0;
    for (int off = 1; off < 1024; off <<= 1) {
        int t = buf[pi][tid] + ((tid >= off) ? buf[pi][tid - off] : 0);
        buf[1 - pi][tid] = t;
        pi = 1 - pi;
        __syncthreads();
    }
    if (i < n) tmp[i] = buf[pi][tid] - v;           // block-local exclusive
    if (tid == 1023) parts[blockIdx.x] = buf[pi][1023];
}

__global__ __launch_bounds__(128) void scanB(
    const int* __restrict__ parts, int* __restrict__ offs,
    int* __restrict__ rowptr, int np, int n)
{
    __shared__ int buf[2][128];
    const int t = threadIdx.x;
    int v = (t < np) ? parts[t] : 0;
    buf[0][t] = v;
    __syncthreads();
    int pi = 0;
    for (int off = 1; off < 128; off <<= 1) {
        int s = buf[pi][t] + ((t >= off) ? buf[pi][t - off] : 0);
        buf[1 - pi][t] = s;
        pi = 1 - pi;
        __syncthreads();
    }
    if (t < np) offs[t] = buf[pi][t] - v;
    if (t == 0) rowptr[n] = buf[pi][127];           // total = n_edges
}

__global__ __launch_bounds__(1024) void scanC(
    const int* __restrict__ tmp, const int* __restrict__ offs,
    int* __restrict__ rowptr, int* __restrict__ cursor, int n)
{
    int i = blockIdx.x * 1024 + threadIdx.x;
    if (i < n) {
        int v = tmp[i] + offs[blockIdx.x];
        rowptr[i] = v;
        cursor[i] = v;
    }
}

// ---------------------------------------------------------------------------
__global__ __launch_bounds__(256) void edge_bin(
    const int* __restrict__ edge_index, const int* __restrict__ edge_type,
    int* __restrict__ cursor, unsigned* __restrict__ pk2, int n_edges)
{
    int e = blockIdx.x * 256 + threadIdx.x;
    if (e >= n_edges) return;
    int src = edge_index[e];
    int dst = edge_index[n_edges + e];
    int r   = edge_type[e];
    int pos = atomicAdd(&cursor[dst], 1);
    pk2[pos] = (unsigned)src | ((unsigned)r << 17);   // src<2^17, rel 3 bits
}

// ---------------------------------------------------------------------------
// Phase 1 v2: H[sgl][node][128] = bf16( X @ WTseg (+bias if seg 0) )
// grid (nxblk, nsegs); each block loops tiles_per_blk 64-row tiles of one
// segment. B-frags live in VGPRs for the whole block (zero B traffic in loop).
// ---------------------------------------------------------------------------
__global__ __launch_bounds__(256, 2) void gemm_h(
    const unsigned* __restrict__ XB, const unsigned short* __restrict__ WT,
    const float* __restrict__ bias, unsigned short* __restrict__ H,
    int n_nodes, int segbase, int ntiles, int tiles_per_blk)
{
    __shared__ unsigned short Ht[2][64][D];    // 2 x 16 KB repack buffers

    const int sgl  = blockIdx.y;               // chunk-local seg
    const int sgg  = segbase + sgl;            // global seg (WT/bias)
    const int tid  = threadIdx.x;
    const int wave = tid >> 6;
    const int lane = tid & 63;
    const int l16  = lane & 15;
    const int quad = lane >> 4;

    // B-frags: register-resident for the whole block (32 x 16B = 128 VGPR)
    bf16x8 bfr[8][4];
    {
        const unsigned short* Wseg = WT + (size_t)sgg * D * D;
#pragma unroll
        for (int nt = 0; nt < 8; ++nt) {
            const unsigned short* bp = Wseg + (size_t)(nt * 16 + l16) * D + quad * 8;
#pragma unroll
            for (int kc = 0; kc < 4; ++kc)
                bfr[nt][kc] = *(const bf16x8*)(bp + kc * 32);
        }
    }
    float bv[8];
#pragma unroll
    for (int nt = 0; nt < 8; ++nt)
        bv[nt] = (sgg == 0) ? bias[nt * 16 + l16] : 0.f;

    const int t0 = blockIdx.x * tiles_per_blk;
    for (int t = 0; t < tiles_per_blk; ++t) {
        const int tile = t0 + t;
        if (tile >= ntiles) break;
        const int m0 = tile * 64;

        // A-frags straight from XB (per-wave private; no barrier dependency)
        const int node = m0 + wave * 16 + l16;
        const bool okr = (node < n_nodes);
        const unsigned short* xr = (const unsigned short*)XB + (size_t)node * D + quad * 8;
        bf16x8 af[4];
#pragma unroll
        for (int kc = 0; kc < 4; ++kc)
            af[kc] = okr ? *(const bf16x8*)(xr + kc * 32)
                         : (bf16x8){0, 0, 0, 0, 0, 0, 0, 0};

        f32x4 acc[8];
#pragma unroll
        for (int nt = 0; nt < 8; ++nt) {
            acc[nt] = (f32x4){0.f, 0.f, 0.f, 0.f};
#pragma unroll
            for (int kc = 0; kc < 4; ++kc)
                acc[nt] = __builtin_amdgcn_mfma_f32_16x16x32_bf16(
                    af[kc], bfr[nt][kc], acc[nt], 0, 0, 0);
        }

        // repack C/D layout -> row-major bf16 tile (double-buffered)
        unsigned short (*Hb)[D] = Ht[t & 1];
#pragma unroll
        for (int nt = 0; nt < 8; ++nt) {
            int col = nt * 16 + l16;
#pragma unroll
            for (int reg = 0; reg < 4; ++reg)
                Hb[wave * 16 + quad * 4 + reg][col] = f32_to_bf16(acc[nt][reg] + bv[nt]);
        }
        lds_barrier();   // orders ds ops only; stores/loads stay in flight

        // coalesced store (uint4 = 8 bf16); fire-and-forget
        int rows = n_nodes - m0; if (rows > 64) rows = 64;
        int nu4 = rows * D / 8;
        const uint4* srcp = (const uint4*)&Hb[0][0];
        uint4* dstp = (uint4*)(H + ((size_t)sgl * n_nodes + m0) * D);
        for (int i = tid; i < nu4; i += 256) dstp[i] = srcp[i];
        // buffer Hb is not rewritten until t+2; the barrier at t+1 separates
        // this tile's LDS reads from that rewrite.
    }
}

// ---------------------------------------------------------------------------
// Phase 2: one wave per dst node. No LDS, no barriers, no atomics.
// lane owns cols {2*lane, 2*lane+1}.
// ---------------------------------------------------------------------------
__global__ __launch_bounds__(256) void gather_out(
    const unsigned short* __restrict__ H, const unsigned* __restrict__ pk2,
    const int* __restrict__ rowptr, const int* __restrict__ c,
    float* __restrict__ out, int n_nodes, int n_rel,
    int segbase, int segend, int first, int last)
{
    const int dst  = (blockIdx.x * 256 + threadIdx.x) >> 6;
    const int lane = threadIdx.x & 63;
    if (dst >= n_nodes) return;

    const unsigned* HH = (const unsigned*)H;
    float a0, a1;
    if (first) {                                   // seg 0 (root+bias) is chunk-local 0
        unsigned u = HH[(size_t)dst * 64 + lane];
        a0 = bf_lo(u); a1 = bf_hi(u);
    } else {
        float2 o = *(const float2*)(out + (size_t)dst * D + 2 * lane);
        a0 = o.x; a1 = o.y;
    }

    const int e0 = rowptr[dst], e1 = rowptr[dst + 1];
    const int s0 = first ? 1 : segbase;            // relation segs in this pass
    for (int base = e0; base < e1; base += 8) {
        unsigned hv[8]; float al[8]; bool ok[8];
#pragma unroll
        for (int j = 0; j < 8; ++j) {
            int e = base + j;
            bool valid = (e < e1);
            unsigned p = valid ? pk2[e] : 0u;
            int r = (int)(p >> 17);
            int seg = r + 1;
            ok[j] = valid && (seg >= s0) && (seg < segend);
            int src = (int)(p & 0x1FFFF);
            al[j] = ok[j] ? 1.0f / (float)c[dst * n_rel + r] : 0.f;
            hv[j] = ok[j] ? HH[((size_t)(seg - segbase) * n_nodes + src) * 64 + lane] : 0u;
        }
#pragma unroll
        for (int j = 0; j < 8; ++j) {
            if (ok[j]) {
                a0 += al[j] * bf_lo(hv[j]);
                a1 += al[j] * bf_hi(hv[j]);
            }
        }
    }

    if (last) { a0 = fmaxf(a0, 0.f); a1 = fmaxf(a1, 0.f); }
    *(float2*)(out + (size_t)dst * D + 2 * lane) = make_float2(a0, a1);
}

extern "C" void kernel_launch(void* const* d_in, const int* in_sizes, int n_in,
                              void* d_out, int out_size, void* d_ws, size_t ws_size,
                              hipStream_t stream) {
    const float* x          = (const float*)d_in[0];
    const int*   edge_index = (const int*)d_in[1];
    const int*   edge_type  = (const int*)d_in[2];
    const float* W          = (const float*)d_in[3];
    const float* root       = (const float*)d_in[4];
    const float* bias       = (const float*)d_in[5];
    float* out = (float*)d_out;

    const int n_nodes = in_sizes[0] / D;          // 100000
    const int n_edges = in_sizes[2];              // 600000
    const int n_rel   = in_sizes[3] / (D * D);    // 8
    const int nsegs   = n_rel + 1;

    // ws layout
    char* p = (char*)d_ws;
    auto alloc = [&](size_t bytes) {
        char* q = p; p += (bytes + 255) & ~(size_t)255; return q;
    };
    int* c      = (int*)alloc((size_t)n_nodes * n_rel * 4);
    int* hd     = (int*)alloc((size_t)n_nodes * 4);
    int* tmp    = (int*)alloc((size_t)n_nodes * 4);
    int* parts  = (int*)alloc(512);
    int* offs   = (int*)alloc(512);
    int* rowptr = (int*)alloc((size_t)(n_nodes + 1) * 4);
    int* cursor = (int*)alloc((size_t)n_nodes * 4);
    unsigned* pk2 = (unsigned*)alloc((size_t)n_edges * 4);
    unsigned* XB  = (unsigned*)alloc((size_t)n_nodes * (D / 2) * 4);
    unsigned short* WT = (unsigned short*)alloc((size_t)nsegs * D * D * 2);
    size_t used = (size_t)(p - (char*)d_ws);
    size_t per_seg = (((size_t)n_nodes * D * 2) + 255) & ~(size_t)255;
    size_t avail = (ws_size > used) ? ws_size - used : 0;
    int segchunk = (int)(avail / per_seg);
    if (segchunk > nsegs) segchunk = nsegs;
    if (segchunk < 1) segchunk = 1;
    unsigned short* H = (unsigned short*)p;

    const int nquads   = n_nodes * (D / 4);
    const int wt_total = nsegs * D * D;
    int prep_n = nquads;
    if (wt_total > prep_n) prep_n = wt_total;
    if (n_nodes * n_rel > prep_n) prep_n = n_nodes * n_rel;

    const int egrid = (n_edges + 255) / 256;
    const int nA = (n_nodes + 1023) / 1024;       // 98 <= 128

    prep_all<<<(prep_n + 255) / 256, 256, 0, stream>>>(
        x, W, root, XB, WT, c, hd, nquads, wt_total, n_nodes, n_rel);
    edge_hist<<<egrid, 256, 0, stream>>>(edge_index, edge_type, c, hd, n_edges, n_rel);
    scanA<<<nA, 1024, 0, stream>>>(hd, tmp, parts, n_nodes);
    scanB<<<1, 128, 0, stream>>>(parts, offs, rowptr, nA, n_nodes);
    scanC<<<nA, 1024, 0, stream>>>(tmp, offs, rowptr, cursor, n_nodes);
    edge_bin<<<egrid, 256, 0, stream>>>(edge_index, edge_type, cursor, pk2, n_edges);

    const int ntiles = (n_nodes + 63) / 64;       // 1563
    const int nxblk  = 56;                        // ~2 blocks/CU with 9 segs
    const int tpb    = (ntiles + nxblk - 1) / nxblk;
    const int ggrid  = (n_nodes + 3) / 4;         // 4 dst-waves per block
    for (int sb = 0; sb < nsegs; sb += segchunk) {
        int sc = nsegs - sb; if (sc > segchunk) sc = segchunk;
        gemm_h<<<dim3(nxblk, sc), 256, 0, stream>>>(
            XB, WT, bias, H, n_nodes, sb, ntiles, tpb);
        gather_out<<<ggrid, 256, 0, stream>>>(
            H, pk2, rowptr, c, out, n_nodes, n_rel,
            sb, sb + sc, (sb == 0) ? 1 : 0, (sb + sc == nsegs) ? 1 : 0);
    }
}

// Round 10
// 349.389 us; speedup vs baseline: 2.4068x; 1.0695x over previous
//
#include <hip/hip_runtime.h>

// RGCN layer: out[i] = relu( x[i]@root + bias + sum_r mean_{j in N_r(i)} x[j]@W[r] )
//
// Two-phase (linearity) + SOURCE COMPACTION:
//   H row layout: rows [0, N) = bf16(x@root + bias); then for each rel r, one
//   row per USED source node: bf16(x[src]@W[r]) (~52.8k rows/rel vs 100k).
//   out[i] = relu( H[i] + sum_{e: dst=i} (1/c[i,r_e]) * H[hidx_e] )
// pk2 packs hidx(20b) | c(8b): gather does no c[] lookup, no masks.
// Prep: one fused 900k two-level scan (CSR rowptr + compaction index),
// scanC folded into consumers, csrc built in edge_bin. 7 launches total.

#define D 128

typedef __attribute__((ext_vector_type(8))) short bf16x8;
typedef __attribute__((ext_vector_type(4))) float f32x4;

__device__ inline unsigned short f32_to_bf16(float f) {
    unsigned u = __float_as_uint(f);
    return (unsigned short)((u + 0x7FFF + ((u >> 16) & 1)) >> 16);   // RNE
}
__device__ inline float bf_lo(unsigned u) { return __uint_as_float(u << 16); }
__device__ inline float bf_hi(unsigned u) { return __uint_as_float(u & 0xFFFF0000u); }

// LDS-only barrier: order ds ops without draining vmcnt.
__device__ inline void lds_barrier() {
    asm volatile("s_waitcnt lgkmcnt(0)\n\ts_barrier" ::: "memory");
}

// ---------------------------------------------------------------------------
// prep: XB = bf16(x); WT[seg][n][k] = bf16(Wseg[k][n]); zero c, G, cnt2
//   G = [ hd(n_nodes) | used(n_rel*n_nodes) ]  (concatenated scan input)
// ---------------------------------------------------------------------------
__global__ __launch_bounds__(256) void prep_all(
    const float* __restrict__ x, const float* __restrict__ W,
    const float* __restrict__ root,
    unsigned* __restrict__ XB, unsigned short* __restrict__ WT,
    int* __restrict__ c, int* __restrict__ G, int* __restrict__ cnt2,
    int nquads, int wt_total, int n_nodes, int n_rel)
{
    int i = blockIdx.x * 256 + threadIdx.x;
    if (i < nquads) {
        float4 v = ((const float4*)x)[i];
        unsigned w0 = (unsigned)f32_to_bf16(v.x) | ((unsigned)f32_to_bf16(v.y) << 16);
        unsigned w1 = (unsigned)f32_to_bf16(v.z) | ((unsigned)f32_to_bf16(v.w) << 16);
        ((uint2*)XB)[i] = make_uint2(w0, w1);
    }
    if (i < wt_total) {
        int seg = i >> 14, rem = i & 16383;
        int n = rem >> 7, k = rem & 127;
        float v = (seg == 0) ? root[k * D + n]
                             : W[(size_t)(seg - 1) * D * D + k * D + n];
        WT[i] = f32_to_bf16(v);
    }
    if (i < n_nodes * n_rel) c[i] = 0;
    if (i < n_nodes * (n_rel + 1)) G[i] = 0;
    if (i < n_nodes) cnt2[i] = 0;
}

// ---------------------------------------------------------------------------
__global__ __launch_bounds__(256) void edge_hist(
    const int* __restrict__ edge_index, const int* __restrict__ edge_type,
    int* __restrict__ c, int* __restrict__ G, int n_edges, int n_nodes, int n_rel)
{
    int e = blockIdx.x * 256 + threadIdx.x;
    if (e >= n_edges) return;
    int src = edge_index[e];
    int dst = edge_index[n_edges + e];
    int r   = edge_type[e];
    atomicAdd(&c[dst * n_rel + r], 1);
    atomicAdd(&G[dst], 1);                       // degree (CSR)
    G[n_nodes + r * n_nodes + src] = 1;          // used flag (benign race)
}

// ---------------------------------------------------------------------------
// Two-level exclusive scan over G[nG]: tmp = block-local exclusive,
// parts = block sums. Consumers compute S(i) = tmp[i] + offs[i>>10].
// ---------------------------------------------------------------------------
__global__ __launch_bounds__(1024) void scanA(
    const int* __restrict__ G, int* __restrict__ tmp, int* __restrict__ parts, int n)
{
    __shared__ int buf[2][1024];
    const int tid = threadIdx.x;
    int i = blockIdx.x * 1024 + tid;
    int v = (i < n) ? G[i] : 0;
    buf[0][tid] = v;
    __syncthreads();
    int pi = 0;
    for (int off = 1; off < 1024; off <<= 1) {
        int t = buf[pi][tid] + ((tid >= off) ? buf[pi][tid - off] : 0);
        buf[1 - pi][tid] = t;
        pi = 1 - pi;
        __syncthreads();
    }
    if (i < n) tmp[i] = buf[pi][tid] - v;
    if (tid == 1023) parts[blockIdx.x] = buf[pi][1023];
}

__global__ __launch_bounds__(1024) void scanB(
    const int* __restrict__ parts, int* __restrict__ offs,
    int* __restrict__ tot, int np)
{
    __shared__ int buf[2][1024];
    const int t = threadIdx.x;
    int v = (t < np) ? parts[t] : 0;
    buf[0][t] = v;
    __syncthreads();
    int pi = 0;
    for (int off = 1; off < 1024; off <<= 1) {
        int s = buf[pi][t] + ((t >= off) ? buf[pi][t - off] : 0);
        buf[1 - pi][t] = s;
        pi = 1 - pi;
        __syncthreads();
    }
    if (t < np) offs[t] = buf[pi][t] - v;
    if (t == 0) tot[0] = buf[pi][1023];          // n_edges + n_compact
}

// ---------------------------------------------------------------------------
// edge_bin: CSR-place each edge; pack hidx|c; build csrc (redundant stores ok)
// ---------------------------------------------------------------------------
__global__ __launch_bounds__(256) void edge_bin(
    const int* __restrict__ edge_index, const int* __restrict__ edge_type,
    const int* __restrict__ tmp, const int* __restrict__ offs,
    const int* __restrict__ c, int* __restrict__ cnt2,
    unsigned* __restrict__ pk2, int* __restrict__ csrc,
    int n_edges, int n_nodes, int n_rel)
{
    int e = blockIdx.x * 256 + threadIdx.x;
    if (e >= n_edges) return;
    int src = edge_index[e];
    int dst = edge_index[n_edges + e];
    int r   = edge_type[e];
    int pos = tmp[dst] + offs[dst >> 10] + atomicAdd(&cnt2[dst], 1);
    int gi  = n_nodes + r * n_nodes + src;
    int cidx = tmp[gi] + offs[gi >> 10] - n_edges;    // compact rel-row index
    int hidx = n_nodes + cidx;                        // < 700000 < 2^20
    unsigned cc = (unsigned)c[dst * n_rel + r];
    if (cc > 255u) cc = 255u;
    pk2[pos] = (unsigned)hidx | (cc << 20);
    csrc[cidx] = src;                                 // same-value race: benign
}

// ---------------------------------------------------------------------------
// Phase 1: H rows. grid (56, n_rel+1). seg 0: all nodes (x@root + bias);
// seg>0: only used srcs of rel seg-1 (via csrc). B-frags register-resident.
// ---------------------------------------------------------------------------
__global__ __launch_bounds__(256, 2) void gemm_h(
    const unsigned* __restrict__ XB, const unsigned short* __restrict__ WT,
    const float* __restrict__ bias, const int* __restrict__ csrc,
    const int* __restrict__ tmp, const int* __restrict__ offs,
    const int* __restrict__ tot, unsigned short* __restrict__ H,
    int n_nodes, int n_edges, int n_rel)
{
    __shared__ unsigned short Ht[2][64][D];

    const int seg  = blockIdx.y;
    const int tid  = threadIdx.x;
    const int wave = tid >> 6;
    const int lane = tid & 63;
    const int l16  = lane & 15;
    const int quad = lane >> 4;

    int base_row, count, segS0 = 0;
    if (seg == 0) { base_row = 0; count = n_nodes; }
    else {
        int r = seg - 1;
        int gi0 = n_nodes + r * n_nodes;
        segS0 = tmp[gi0] + offs[gi0 >> 10] - n_edges;
        int segS1;
        if (r == n_rel - 1) segS1 = tot[0] - n_edges;
        else { int gi1 = gi0 + n_nodes; segS1 = tmp[gi1] + offs[gi1 >> 10] - n_edges; }
        base_row = n_nodes + segS0;
        count = segS1 - segS0;
    }

    // B-frags: register-resident for the whole block (32 x 16B = 128 VGPR)
    bf16x8 bfr[8][4];
    {
        const unsigned short* Wseg = WT + (size_t)seg * D * D;
#pragma unroll
        for (int nt = 0; nt < 8; ++nt) {
            const unsigned short* bp = Wseg + (size_t)(nt * 16 + l16) * D + quad * 8;
#pragma unroll
            for (int kc = 0; kc < 4; ++kc)
                bfr[nt][kc] = *(const bf16x8*)(bp + kc * 32);
        }
    }
    float bv[8];
#pragma unroll
    for (int nt = 0; nt < 8; ++nt)
        bv[nt] = (seg == 0) ? bias[nt * 16 + l16] : 0.f;

    int it = 0;
    for (int tile = blockIdx.x; tile * 64 < count; tile += gridDim.x, ++it) {
        const int lr = tile * 64 + wave * 16 + l16;
        const bool valid = (lr < count);
        int node = 0;
        if (valid) node = (seg == 0) ? lr : csrc[segS0 + lr];

        const unsigned short* xr = (const unsigned short*)XB + (size_t)node * D + quad * 8;
        bf16x8 af[4];
#pragma unroll
        for (int kc = 0; kc < 4; ++kc)
            af[kc] = valid ? *(const bf16x8*)(xr + kc * 32)
                           : (bf16x8){0, 0, 0, 0, 0, 0, 0, 0};

        f32x4 acc[8];
#pragma unroll
        for (int nt = 0; nt < 8; ++nt) {
            acc[nt] = (f32x4){0.f, 0.f, 0.f, 0.f};
#pragma unroll
            for (int kc = 0; kc < 4; ++kc)
                acc[nt] = __builtin_amdgcn_mfma_f32_16x16x32_bf16(
                    af[kc], bfr[nt][kc], acc[nt], 0, 0, 0);
        }

        unsigned short (*Hb)[D] = Ht[it & 1];
#pragma unroll
        for (int nt = 0; nt < 8; ++nt) {
            int col = nt * 16 + l16;
#pragma unroll
            for (int reg = 0; reg < 4; ++reg)
                Hb[wave * 16 + quad * 4 + reg][col] = f32_to_bf16(acc[nt][reg] + bv[nt]);
        }
        lds_barrier();   // ds-order only; global stores/loads stay in flight

        int rows = count - tile * 64; if (rows > 64) rows = 64;
        int nu4 = rows * (D / 8);
        const uint4* srcp = (const uint4*)&Hb[0][0];
        uint4* dstp = (uint4*)(H + ((size_t)(base_row + tile * 64)) * D);
        for (int i = tid; i < nu4; i += 256) dstp[i] = srcp[i];
    }
}

// ---------------------------------------------------------------------------
// Phase 2: one wave per dst node. No LDS/barriers/atomics/c-lookups.
// lane owns cols {2*lane, 2*lane+1}. Weight 1/c unpacked from pk2.
// ---------------------------------------------------------------------------
__global__ __launch_bounds__(256) void gather_out(
    const unsigned short* __restrict__ H, const unsigned* __restrict__ pk2,
    const int* __restrict__ tmp, const int* __restrict__ offs,
    float* __restrict__ out, int n_nodes)
{
    const int dst  = (blockIdx.x * 256 + threadIdx.x) >> 6;
    const int lane = threadIdx.x & 63;
    if (dst >= n_nodes) return;

    const unsigned* HH = (const unsigned*)H;
    unsigned u0 = HH[(size_t)dst * 64 + lane];        // root+bias row
    float a0 = bf_lo(u0), a1 = bf_hi(u0);

    const int e0 = tmp[dst] + offs[dst >> 10];
    const int e1 = tmp[dst + 1] + offs[(dst + 1) >> 10];

    for (int base = e0; base < e1; base += 8) {
        unsigned hv[8]; float al[8]; bool ok[8];
#pragma unroll
        for (int j = 0; j < 8; ++j) {
            int e = base + j;
            ok[j] = (e < e1);
            unsigned p = ok[j] ? pk2[e] : 0u;
            al[j] = ok[j] ? 1.0f / (float)(p >> 20) : 0.f;
            hv[j] = ok[j] ? HH[(size_t)(p & 0xFFFFFu) * 64 + lane] : 0u;
        }
#pragma unroll
        for (int j = 0; j < 8; ++j) {
            if (ok[j]) {
                a0 += al[j] * bf_lo(hv[j]);
                a1 += al[j] * bf_hi(hv[j]);
            }
        }
    }

    a0 = fmaxf(a0, 0.f); a1 = fmaxf(a1, 0.f);
    *(float2*)(out + (size_t)dst * D + 2 * lane) = make_float2(a0, a1);
}

extern "C" void kernel_launch(void* const* d_in, const int* in_sizes, int n_in,
                              void* d_out, int out_size, void* d_ws, size_t ws_size,
                              hipStream_t stream) {
    const float* x          = (const float*)d_in[0];
    const int*   edge_index = (const int*)d_in[1];
    const int*   edge_type  = (const int*)d_in[2];
    const float* W          = (const float*)d_in[3];
    const float* root       = (const float*)d_in[4];
    const float* bias       = (const float*)d_in[5];
    float* out = (float*)d_out;

    const int n_nodes = in_sizes[0] / D;          // 100000
    const int n_edges = in_sizes[2];              // 600000
    const int n_rel   = in_sizes[3] / (D * D);    // 8
    const int nsegs   = n_rel + 1;
    const int nG      = n_nodes * nsegs;          // 900000

    // ws layout (worst-case compact rows = n_nodes + n_edges)
    char* p = (char*)d_ws;
    auto alloc = [&](size_t bytes) {
        char* q = p; p += (bytes + 255) & ~(size_t)255; return q;
    };
    int* c      = (int*)alloc((size_t)n_nodes * n_rel * 4);
    int* G      = (int*)alloc((size_t)(nG + 1) * 4);
    int* tmp    = (int*)alloc((size_t)(nG + 1) * 4);
    int* parts  = (int*)alloc(4096);
    int* offs   = (int*)alloc(4096);
    int* tot    = (int*)alloc(256);
    int* cnt2   = (int*)alloc((size_t)n_nodes * 4);
    unsigned* pk2 = (unsigned*)alloc((size_t)n_edges * 4);
    unsigned* XB  = (unsigned*)alloc((size_t)n_nodes * (D / 2) * 4);
    unsigned short* WT = (unsigned short*)alloc((size_t)nsegs * D * D * 2);
    int* csrc   = (int*)alloc((size_t)n_edges * 4);
    unsigned short* H = (unsigned short*)p;       // worst (n_nodes+n_edges) rows

    const int nquads   = n_nodes * (D / 4);
    const int wt_total = nsegs * D * D;
    int prep_n = nquads;
    if (wt_total > prep_n) prep_n = wt_total;
    if (nG > prep_n) prep_n = nG;

    const int egrid = (n_edges + 255) / 256;
    const int nA = (nG + 1023) / 1024;            // 879 <= 1024

    prep_all<<<(prep_n + 255) / 256, 256, 0, stream>>>(
        x, W, root, XB, WT, c, G, cnt2, nquads, wt_total, n_nodes, n_rel);
    edge_hist<<<egrid, 256, 0, stream>>>(
        edge_index, edge_type, c, G, n_edges, n_nodes, n_rel);
    scanA<<<nA, 1024, 0, stream>>>(G, tmp, parts, nG);
    scanB<<<1, 1024, 0, stream>>>(parts, offs, tot, nA);
    edge_bin<<<egrid, 256, 0, stream>>>(
        edge_index, edge_type, tmp, offs, c, cnt2, pk2, csrc,
        n_edges, n_nodes, n_rel);
    gemm_h<<<dim3(56, nsegs), 256, 0, stream>>>(
        XB, WT, bias, csrc, tmp, offs, tot, H, n_nodes, n_edges, n_rel);
    gather_out<<<(n_nodes + 3) / 4, 256, 0, stream>>>(
        H, pk2, tmp, offs, out, n_nodes);
}

// Round 11
// 314.048 us; speedup vs baseline: 2.6777x; 1.1125x over previous
//
#include <hip/hip_runtime.h>

// RGCN layer: out[i] = relu( x[i]@root + bias + sum_r mean_{j in N_r(i)} x[j]@W[r] )
//
// Two-phase (linearity) + SOURCE COMPACTION:
//   H rows [0,N) = bf16(x@root + bias); then per rel r one row per USED src:
//   bf16(x[src]@W[r]).  out[i] = relu( H[i] + sum_e (1/c) * H[hidx_e] )
// pk2 packs hidx(20b) | c(8b). gather v2: wave-uniform dst scalarized
// (readfirstlane -> SMEM loads for pk2/bounds), rcpf for 1/c.
// gemm_h v3: 2-stage pipeline (csrc prefetch dist 2, XB A-frag dist 1).

#define D 128

typedef __attribute__((ext_vector_type(8))) short bf16x8;
typedef __attribute__((ext_vector_type(4))) float f32x4;

__device__ inline unsigned short f32_to_bf16(float f) {
    unsigned u = __float_as_uint(f);
    return (unsigned short)((u + 0x7FFF + ((u >> 16) & 1)) >> 16);   // RNE
}
__device__ inline float bf_lo(unsigned u) { return __uint_as_float(u << 16); }
__device__ inline float bf_hi(unsigned u) { return __uint_as_float(u & 0xFFFF0000u); }

// LDS-only barrier: order ds ops without draining vmcnt.
__device__ inline void lds_barrier() {
    asm volatile("s_waitcnt lgkmcnt(0)\n\ts_barrier" ::: "memory");
}

// ---------------------------------------------------------------------------
// prep: XB = bf16(x); WT[seg][n][k] = bf16(Wseg[k][n]); zero c, G, cnt2
// ---------------------------------------------------------------------------
__global__ __launch_bounds__(256) void prep_all(
    const float* __restrict__ x, const float* __restrict__ W,
    const float* __restrict__ root,
    unsigned* __restrict__ XB, unsigned short* __restrict__ WT,
    int* __restrict__ c, int* __restrict__ G, int* __restrict__ cnt2,
    int nquads, int wt_total, int n_nodes, int n_rel)
{
    int i = blockIdx.x * 256 + threadIdx.x;
    if (i < nquads) {
        float4 v = ((const float4*)x)[i];
        unsigned w0 = (unsigned)f32_to_bf16(v.x) | ((unsigned)f32_to_bf16(v.y) << 16);
        unsigned w1 = (unsigned)f32_to_bf16(v.z) | ((unsigned)f32_to_bf16(v.w) << 16);
        ((uint2*)XB)[i] = make_uint2(w0, w1);
    }
    if (i < wt_total) {
        int seg = i >> 14, rem = i & 16383;
        int n = rem >> 7, k = rem & 127;
        float v = (seg == 0) ? root[k * D + n]
                             : W[(size_t)(seg - 1) * D * D + k * D + n];
        WT[i] = f32_to_bf16(v);
    }
    if (i < n_nodes * n_rel) c[i] = 0;
    if (i < n_nodes * (n_rel + 1)) G[i] = 0;
    if (i < n_nodes) cnt2[i] = 0;
}

// ---------------------------------------------------------------------------
__global__ __launch_bounds__(256) void edge_hist(
    const int* __restrict__ edge_index, const int* __restrict__ edge_type,
    int* __restrict__ c, int* __restrict__ G, int n_edges, int n_nodes, int n_rel)
{
    int e = blockIdx.x * 256 + threadIdx.x;
    if (e >= n_edges) return;
    int src = edge_index[e];
    int dst = edge_index[n_edges + e];
    int r   = edge_type[e];
    atomicAdd(&c[dst * n_rel + r], 1);
    atomicAdd(&G[dst], 1);                       // degree (CSR)
    G[n_nodes + r * n_nodes + src] = 1;          // used flag (benign race)
}

// ---------------------------------------------------------------------------
// Two-level exclusive scan over G[nG]. Consumers: S(i) = tmp[i] + offs[i>>10].
// ---------------------------------------------------------------------------
__global__ __launch_bounds__(1024) void scanA(
    const int* __restrict__ G, int* __restrict__ tmp, int* __restrict__ parts, int n)
{
    __shared__ int buf[2][1024];
    const int tid = threadIdx.x;
    int i = blockIdx.x * 1024 + tid;
    int v = (i < n) ? G[i] : 0;
    buf[0][tid] = v;
    __syncthreads();
    int pi = 0;
    for (int off = 1; off < 1024; off <<= 1) {
        int t = buf[pi][tid] + ((tid >= off) ? buf[pi][tid - off] : 0);
        buf[1 - pi][tid] = t;
        pi = 1 - pi;
        __syncthreads();
    }
    if (i < n) tmp[i] = buf[pi][tid] - v;
    if (tid == 1023) parts[blockIdx.x] = buf[pi][1023];
}

__global__ __launch_bounds__(1024) void scanB(
    const int* __restrict__ parts, int* __restrict__ offs,
    int* __restrict__ tot, int np)
{
    __shared__ int buf[2][1024];
    const int t = threadIdx.x;
    int v = (t < np) ? parts[t] : 0;
    buf[0][t] = v;
    __syncthreads();
    int pi = 0;
    for (int off = 1; off < 1024; off <<= 1) {
        int s = buf[pi][t] + ((t >= off) ? buf[pi][t - off] : 0);
        buf[1 - pi][t] = s;
        pi = 1 - pi;
        __syncthreads();
    }
    if (t < np) offs[t] = buf[pi][t] - v;
    if (t == 0) tot[0] = buf[pi][1023];          // n_edges + n_compact
}

// ---------------------------------------------------------------------------
// edge_bin: CSR-place each edge; pack hidx|c; build csrc (redundant stores ok)
// ---------------------------------------------------------------------------
__global__ __launch_bounds__(256) void edge_bin(
    const int* __restrict__ edge_index, const int* __restrict__ edge_type,
    const int* __restrict__ tmp, const int* __restrict__ offs,
    const int* __restrict__ c, int* __restrict__ cnt2,
    unsigned* __restrict__ pk2, int* __restrict__ csrc,
    int n_edges, int n_nodes, int n_rel)
{
    int e = blockIdx.x * 256 + threadIdx.x;
    if (e >= n_edges) return;
    int src = edge_index[e];
    int dst = edge_index[n_edges + e];
    int r   = edge_type[e];
    int pos = tmp[dst] + offs[dst >> 10] + atomicAdd(&cnt2[dst], 1);
    int gi  = n_nodes + r * n_nodes + src;
    int cidx = tmp[gi] + offs[gi >> 10] - n_edges;    // compact rel-row index
    int hidx = n_nodes + cidx;                        // < 2^20
    unsigned cc = (unsigned)c[dst * n_rel + r];
    if (cc > 255u) cc = 255u;
    pk2[pos] = (unsigned)hidx | (cc << 20);
    csrc[cidx] = src;                                 // same-value race: benign
}

// ---------------------------------------------------------------------------
// Phase 1 v3: H rows, 2-stage pipelined. grid (56, n_rel+1).
// seg 0: all nodes (x@root + bias); seg>0: used srcs of rel seg-1 via csrc.
// B-frags register-resident; csrc prefetch distance 2, XB frag distance 1.
// ---------------------------------------------------------------------------
__global__ __launch_bounds__(256, 2) void gemm_h(
    const unsigned* __restrict__ XB, const unsigned short* __restrict__ WT,
    const float* __restrict__ bias, const int* __restrict__ csrc,
    const int* __restrict__ tmp, const int* __restrict__ offs,
    const int* __restrict__ tot, unsigned short* __restrict__ H,
    int n_nodes, int n_edges, int n_rel)
{
    __shared__ unsigned short Ht[2][64][D];

    const int seg  = blockIdx.y;
    const int tid  = threadIdx.x;
    const int wave = tid >> 6;
    const int lane = tid & 63;
    const int l16  = lane & 15;
    const int quad = lane >> 4;

    int base_row, count, segS0 = 0;
    if (seg == 0) { base_row = 0; count = n_nodes; }
    else {
        int r = seg - 1;
        int gi0 = n_nodes + r * n_nodes;
        segS0 = tmp[gi0] + offs[gi0 >> 10] - n_edges;
        int segS1;
        if (r == n_rel - 1) segS1 = tot[0] - n_edges;
        else { int gi1 = gi0 + n_nodes; segS1 = tmp[gi1] + offs[gi1 >> 10] - n_edges; }
        base_row = n_nodes + segS0;
        count = segS1 - segS0;
    }

    // B-frags: register-resident for the whole block (32 x 16B = 128 VGPR)
    bf16x8 bfr[8][4];
    {
        const unsigned short* Wseg = WT + (size_t)seg * D * D;
#pragma unroll
        for (int nt = 0; nt < 8; ++nt) {
            const unsigned short* bp = Wseg + (size_t)(nt * 16 + l16) * D + quad * 8;
#pragma unroll
            for (int kc = 0; kc < 4; ++kc)
                bfr[nt][kc] = *(const bf16x8*)(bp + kc * 32);
        }
    }
    float bv[8];
#pragma unroll
    for (int nt = 0; nt < 8; ++nt)
        bv[nt] = (seg == 0) ? bias[nt * 16 + l16] : 0.f;

    const int gx = gridDim.x;
    const int row_off = wave * 16 + l16;
    const int cq8 = quad * 8;

    int tile = blockIdx.x;
    if (tile * 64 >= count) return;

    auto load_node = [&](int t) -> int {
        int lr = t * 64 + row_off;
        if (lr >= count) return 0;
        return (seg == 0) ? lr : csrc[segS0 + lr];
    };
    auto load_af = [&](int t, int node, bf16x8* fr) {
        int lr = t * 64 + row_off;
        bool v = (lr < count);
        const unsigned short* xr = (const unsigned short*)XB + (size_t)node * D + cq8;
#pragma unroll
        for (int kc = 0; kc < 4; ++kc)
            fr[kc] = v ? *(const bf16x8*)(xr + kc * 32)
                       : (bf16x8){0, 0, 0, 0, 0, 0, 0, 0};
    };

    int node_cur = load_node(tile);
    bf16x8 af[4];
    load_af(tile, node_cur, af);
    int tile_nxt = tile + gx;
    int node_nxt = (tile_nxt * 64 < count) ? load_node(tile_nxt) : 0;

    int it = 0;
    for (;;) {
        const bool have_nxt = (tile_nxt * 64 < count);

        // (1) issue next tile's A-frag loads (node_nxt resolved last iter)
        bf16x8 afn[4];
        if (have_nxt) load_af(tile_nxt, node_nxt, afn);

        // (2) MFMA current tile (covers afn latency)
        f32x4 acc[8];
#pragma unroll
        for (int nt = 0; nt < 8; ++nt) {
            acc[nt] = (f32x4){0.f, 0.f, 0.f, 0.f};
#pragma unroll
            for (int kc = 0; kc < 4; ++kc)
                acc[nt] = __builtin_amdgcn_mfma_f32_16x16x32_bf16(
                    af[kc], bfr[nt][kc], acc[nt], 0, 0, 0);
        }

        // (3) issue csrc prefetch for tile+2 (covered by repack/store + next MFMA)
        int tile_n2 = tile_nxt + gx;
        int node_n2 = 0;
        if (have_nxt && tile_n2 * 64 < count) node_n2 = load_node(tile_n2);

        // (4) repack C/D -> row-major bf16 tile (double-buffered) + store
        unsigned short (*Hb)[D] = Ht[it & 1];
#pragma unroll
        for (int nt = 0; nt < 8; ++nt) {
            int col = nt * 16 + l16;
#pragma unroll
            for (int reg = 0; reg < 4; ++reg)
                Hb[wave * 16 + quad * 4 + reg][col] = f32_to_bf16(acc[nt][reg] + bv[nt]);
        }
        lds_barrier();   // ds-order only; global stores/loads stay in flight

        int rows = count - tile * 64; if (rows > 64) rows = 64;
        int nu4 = rows * (D / 8);
        const uint4* srcp = (const uint4*)&Hb[0][0];
        uint4* dstp = (uint4*)(H + ((size_t)(base_row + tile * 64)) * D);
        for (int i = tid; i < nu4; i += 256) dstp[i] = srcp[i];

        if (!have_nxt) break;
        tile = tile_nxt; tile_nxt = tile_n2;
        node_cur = node_nxt; node_nxt = node_n2;
#pragma unroll
        for (int kc = 0; kc < 4; ++kc) af[kc] = afn[kc];
        ++it;
    }
}

// ---------------------------------------------------------------------------
// Phase 2 v2: one wave per dst node; dst made explicitly wave-uniform so
// pk2/bounds go through scalar loads; per-lane work = H load + 2 unpack +
// 2 FMA per edge. 1/c via v_rcp (c is a small integer: error ~1 ulp).
// ---------------------------------------------------------------------------
__global__ __launch_bounds__(256) void gather_out(
    const unsigned short* __restrict__ H, const unsigned* __restrict__ pk2,
    const int* __restrict__ tmp, const int* __restrict__ offs,
    float* __restrict__ out, int n_nodes)
{
    int dst = (blockIdx.x * 256 + threadIdx.x) >> 6;
    const int lane = threadIdx.x & 63;
    if (dst >= n_nodes) return;
    dst = __builtin_amdgcn_readfirstlane(dst);   // wave-uniform by construction

    const unsigned* HH = (const unsigned*)H;
    unsigned u0 = HH[(size_t)dst * 64 + lane];   // root+bias row
    float a0 = bf_lo(u0), a1 = bf_hi(u0);

    const int e0 = tmp[dst] + offs[dst >> 10];
    const int e1 = tmp[dst + 1] + offs[(dst + 1) >> 10];

    for (int base = e0; base < e1; base += 8) {
        float al[8];
        const unsigned* hp[8];
#pragma unroll
        for (int j = 0; j < 8; ++j) {
            int e = base + j;
            bool ok = (e < e1);
            unsigned p = ok ? pk2[e] : 0u;       // uniform address -> s_load
            al[j] = ok ? __builtin_amdgcn_rcpf((float)(p >> 20)) : 0.f;
            hp[j] = HH + (size_t)(p & 0xFFFFFu) * 64;
        }
        unsigned hv[8];
#pragma unroll
        for (int j = 0; j < 8; ++j) hv[j] = hp[j][lane];
#pragma unroll
        for (int j = 0; j < 8; ++j) {
            a0 += al[j] * bf_lo(hv[j]);
            a1 += al[j] * bf_hi(hv[j]);
        }
    }

    a0 = fmaxf(a0, 0.f); a1 = fmaxf(a1, 0.f);
    *(float2*)(out + (size_t)dst * D + 2 * lane) = make_float2(a0, a1);
}

extern "C" void kernel_launch(void* const* d_in, const int* in_sizes, int n_in,
                              void* d_out, int out_size, void* d_ws, size_t ws_size,
                              hipStream_t stream) {
    const float* x          = (const float*)d_in[0];
    const int*   edge_index = (const int*)d_in[1];
    const int*   edge_type  = (const int*)d_in[2];
    const float* W          = (const float*)d_in[3];
    const float* root       = (const float*)d_in[4];
    const float* bias       = (const float*)d_in[5];
    float* out = (float*)d_out;

    const int n_nodes = in_sizes[0] / D;          // 100000
    const int n_edges = in_sizes[2];              // 600000
    const int n_rel   = in_sizes[3] / (D * D);    // 8
    const int nsegs   = n_rel + 1;
    const int nG      = n_nodes * nsegs;          // 900000

    // ws layout (worst-case compact rows = n_nodes + n_edges)
    char* p = (char*)d_ws;
    auto alloc = [&](size_t bytes) {
        char* q = p; p += (bytes + 255) & ~(size_t)255; return q;
    };
    int* c      = (int*)alloc((size_t)n_nodes * n_rel * 4);
    int* G      = (int*)alloc((size_t)(nG + 1) * 4);
    int* tmp    = (int*)alloc((size_t)(nG + 1) * 4);
    int* parts  = (int*)alloc(4096);
    int* offs   = (int*)alloc(4096);
    int* tot    = (int*)alloc(256);
    int* cnt2   = (int*)alloc((size_t)n_nodes * 4);
    unsigned* pk2 = (unsigned*)alloc((size_t)n_edges * 4);
    unsigned* XB  = (unsigned*)alloc((size_t)n_nodes * (D / 2) * 4);
    unsigned short* WT = (unsigned short*)alloc((size_t)nsegs * D * D * 2);
    int* csrc   = (int*)alloc((size_t)n_edges * 4);
    unsigned short* H = (unsigned short*)p;       // worst (n_nodes+n_edges) rows

    const int nquads   = n_nodes * (D / 4);
    const int wt_total = nsegs * D * D;
    int prep_n = nquads;
    if (wt_total > prep_n) prep_n = wt_total;
    if (nG > prep_n) prep_n = nG;

    const int egrid = (n_edges + 255) / 256;
    const int nA = (nG + 1023) / 1024;            // 879 <= 1024

    prep_all<<<(prep_n + 255) / 256, 256, 0, stream>>>(
        x, W, root, XB, WT, c, G, cnt2, nquads, wt_total, n_nodes, n_rel);
    edge_hist<<<egrid, 256, 0, stream>>>(
        edge_index, edge_type, c, G, n_edges, n_nodes, n_rel);
    scanA<<<nA, 1024, 0, stream>>>(G, tmp, parts, nG);
    scanB<<<1, 1024, 0, stream>>>(parts, offs, tot, nA);
    edge_bin<<<egrid, 256, 0, stream>>>(
        edge_index, edge_type, tmp, offs, c, cnt2, pk2, csrc,
        n_edges, n_nodes, n_rel);
    gemm_h<<<dim3(56, nsegs), 256, 0, stream>>>(
        XB, WT, bias, csrc, tmp, offs, tot, H, n_nodes, n_edges, n_rel);
    gather_out<<<(n_nodes + 3) / 4, 256, 0, stream>>>(
        H, pk2, tmp, offs, out, n_nodes);
}